// Round 1
// 139.610 us; speedup vs baseline: 1.0126x; 1.0126x over previous
//
#include <hip/hip_runtime.h>
#include <hip/hip_bf16.h>
#include <math.h>

#define N 4096
#define K 2048
#define NC 32
#define MARGIN 0.3f

#define BK 128           // K elements per pipeline stage
#define NITER (K / BK)   // 16
#define DIAG_BLOCKS 192  // 32 classes x 6 upper-tri sub-tile pairs of 64
#define CROSS_BLOCKS 192 // 3 row-tiles x 64 col-tiles
#define GRID (DIAG_BLOCKS + CROSS_BLOCKS)

typedef float f32x4 __attribute__((ext_vector_type(4)));
typedef __bf16 bf16x8 __attribute__((ext_vector_type(8)));

__device__ __forceinline__ void glds16(const void* g, void* l) {
  __builtin_amdgcn_global_load_lds(
      (const __attribute__((address_space(1))) void*)g,
      (__attribute__((address_space(3))) void*)l, 16, 0, 0);
}

__device__ __forceinline__ int imin(int a, int b) { return a < b ? a : b; }

// ---------------------------------------------------------------------------
// Kernel 0: class histogram -> offsets/cursors, row0_has_zero flag, done=0.
// ---------------------------------------------------------------------------
__global__ __launch_bounds__(256) void hist_kernel(
    const int* __restrict__ tg, int* __restrict__ cnt, int* __restrict__ off,
    int* __restrict__ cursor, int* __restrict__ flag, int* __restrict__ done) {
  __shared__ int h[NC];
  int t = threadIdx.x;
  if (t < NC) h[t] = 0;
  __syncthreads();
  const int4* tg4 = (const int4*)tg;
  for (int i = t; i < N / 4; i += 256) {
    int4 v = tg4[i];
    atomicAdd(&h[v.x], 1); atomicAdd(&h[v.y], 1);
    atomicAdd(&h[v.z], 1); atomicAdd(&h[v.w], 1);
  }
  __syncthreads();
  if (t == 0) {
    int acc = 0;
    for (int c = 0; c < NC; c++) {
      cnt[c] = h[c];
      off[c] = acc;
      cursor[c] = acc;
      acc += h[c];
    }
    int t0 = tg[0];
    flag[0] = (t0 == 0) ? (N - h[0] > 0) : (h[0] > 0);
    done[0] = 0;
  }
}

// ---------------------------------------------------------------------------
// Kernel 1: fp32 -> bf16 convert + class-sorted scatter + sum-of-squares +
// ap/an init. One WAVE per original row (no block-wide syncs, no LDS):
// 1024 blocks x 4 waves.
// ---------------------------------------------------------------------------
__global__ __launch_bounds__(256) void convert_kernel(
    const float* __restrict__ X, const int* __restrict__ tg,
    __bf16* __restrict__ Xg, float* __restrict__ sqg,
    unsigned int* __restrict__ ap, unsigned int* __restrict__ an,
    int* __restrict__ cursor) {
  int t = threadIdx.x;
  int row = blockIdx.x * 4 + (t >> 6);
  int lane = t & 63;
  const float4* xr = (const float4*)(X + (size_t)row * K);

  // 8 float4 loads in flight (lane covers 4 chunks of 8 floats).
  float4 v[8];
  #pragma unroll
  for (int q = 0; q < 4; q++) {
    int chunk = q * 64 + lane;
    v[2 * q]     = xr[chunk * 2];
    v[2 * q + 1] = xr[chunk * 2 + 1];
  }

  float s = 0.f;
  bf16x8 b[4];
  #pragma unroll
  for (int q = 0; q < 4; q++) {
    float4 a0 = v[2 * q], a1 = v[2 * q + 1];
    s += a0.x * a0.x + a0.y * a0.y + a0.z * a0.z + a0.w * a0.w +
         a1.x * a1.x + a1.y * a1.y + a1.z * a1.z + a1.w * a1.w;
    b[q][0] = (__bf16)a0.x; b[q][1] = (__bf16)a0.y;
    b[q][2] = (__bf16)a0.z; b[q][3] = (__bf16)a0.w;
    b[q][4] = (__bf16)a1.x; b[q][5] = (__bf16)a1.y;
    b[q][6] = (__bf16)a1.z; b[q][7] = (__bf16)a1.w;
  }

  #pragma unroll
  for (int m = 32; m; m >>= 1) s += __shfl_xor(s, m);

  int pos = 0;
  if (lane == 0) pos = atomicAdd(&cursor[tg[row]], 1);
  pos = __shfl(pos, 0);

  bf16x8* dst = (bf16x8*)(Xg + (size_t)pos * K);
  #pragma unroll
  for (int q = 0; q < 4; q++) dst[q * 64 + lane] = b[q];

  if (lane == 0) {
    sqg[pos] = s;
    ap[pos] = 0u;           // identity for max of non-negative floats
    an[pos] = 0x7f800000u;  // +inf
  }
}

// ---------------------------------------------------------------------------
// Kernel 2: class-bucketed 64x64 MFMA tiles, BK=128, double-buffered async
// global_load_lds pipeline with raw s_barrier + manual vmcnt (prefetch stays
// in flight across the barrier). XOR-swizzled LDS.
// Diag blocks enumerate only the UPPER TRIANGLE of sub-tile pairs
// (dist(i,j)==dist(j,i) bit-exactly); off-diagonal sub-tiles update ap from
// both the row-max and the column-max. Last block (ticket) does the final
// loss reduction.
// ---------------------------------------------------------------------------
__global__ __launch_bounds__(256) void gemm_reduce_kernel(
    const __bf16* __restrict__ Xg, const float* __restrict__ sqg,
    const int* __restrict__ cnt, const int* __restrict__ off,
    unsigned int* __restrict__ ap, unsigned int* __restrict__ an,
    const int* __restrict__ flag, int* __restrict__ done,
    float* __restrict__ out) {
  __shared__ __align__(16) __bf16 sA[2][64 * BK];  // 2 x 16 KiB
  __shared__ __align__(16) __bf16 sB[2][64 * BK];
  __shared__ int s_islast;
  __shared__ float wred[4];

  int b = blockIdx.x;
  int t = threadIdx.x;

  bool active = true, diag = true, dcol = false;
  int i0g = 0, iend = 1, j0g = 0, jend = 1;
  if (b < DIAG_BLOCKS) {
    int c = b / 6, p = b % 6;
    // p -> (sti,stj): (0,0),(0,1),(0,2),(1,1),(1,2),(2,2)
    int sti = (p < 3) ? 0 : (p < 5 ? 1 : 2);
    int stj = (p < 3) ? p : (p < 5 ? p - 2 : 2);
    int o = off[c], n = cnt[c];
    if (n == 0 || sti * 64 >= n || stj * 64 >= n) active = false;
    i0g = o + sti * 64; iend = o + n;
    j0g = o + stj * 64; jend = o + n;
    dcol = (sti != stj);
  } else {
    int idx = b - DIAG_BLOCKS;
    int it = idx >> 6, jt = idx & 63;
    int n0 = cnt[0];
    int j0 = n0 + jt * 64;
    if (n0 == 0 || it * 64 >= n0 || j0 >= N) active = false;
    i0g = it * 64; iend = n0;
    j0g = j0; jend = N;
    diag = false;
  }

  if (active) {
    int w = t >> 6, l = t & 63;
    int wi = w >> 1, wj = w & 1;
    int quad = l >> 4, lr = l & 15;

    // Staging: thread t fills LDS (row_l = r*16 + t>>4, cb_l = t&15) from
    // global col-block cb_g = cb_l ^ (row_l & 15). row_l&15 == t>>4.
    const char* gA[4]; const char* gB[4];
    int rr = t >> 4, cbl = t & 15;
    int cbg = cbl ^ rr;
    #pragma unroll
    for (int r = 0; r < 4; r++) {
      int row_l = r * 16 + rr;
      int ra = imin(i0g + row_l, iend - 1);
      int rb = imin(j0g + row_l, jend - 1);
      gA[r] = (const char*)(Xg + (size_t)ra * K) + cbg * 16;
      gB[r] = (const char*)(Xg + (size_t)rb * K) + cbg * 16;
    }

    // Fragment LDS byte offsets: row*256 + (cb ^ (row&15))*16, row&15 == lr.
    int aoff[2][4], boff[2][4];
    #pragma unroll
    for (int ti = 0; ti < 2; ti++)
      #pragma unroll
      for (int kc = 0; kc < 4; kc++) {
        int cb = kc * 4 + quad;
        int sw = (cb ^ lr) * 16;
        aoff[ti][kc] = (wi * 32 + ti * 16 + lr) * 256 + sw;
        boff[ti][kc] = (wj * 32 + ti * 16 + lr) * 256 + sw;
      }

    f32x4 acc[2][2];
    acc[0][0] = (f32x4)0.f; acc[0][1] = (f32x4)0.f;
    acc[1][0] = (f32x4)0.f; acc[1][1] = (f32x4)0.f;

    auto stage = [&](int buf, int itk) {
      int koff = itk * (BK * 2);
      char* la = (char*)sA + buf * 16384 + t * 16;
      char* lb = (char*)sB + buf * 16384 + t * 16;
      #pragma unroll
      for (int r = 0; r < 4; r++) {
        glds16(gA[r] + koff, la + r * 4096);
        glds16(gB[r] + koff, lb + r * 4096);
      }
    };

    auto compute = [&](int buf) {
      const char* bufA = (const char*)sA + buf * 16384;
      const char* bufB = (const char*)sB + buf * 16384;
      #pragma unroll
      for (int kc = 0; kc < 4; kc++) {
        bf16x8 a0 = *(const bf16x8*)(bufA + aoff[0][kc]);
        bf16x8 a1 = *(const bf16x8*)(bufA + aoff[1][kc]);
        bf16x8 b0 = *(const bf16x8*)(bufB + boff[0][kc]);
        bf16x8 b1 = *(const bf16x8*)(bufB + boff[1][kc]);
        acc[0][0] = __builtin_amdgcn_mfma_f32_16x16x32_bf16(a0, b0, acc[0][0], 0, 0, 0);
        acc[0][1] = __builtin_amdgcn_mfma_f32_16x16x32_bf16(a0, b1, acc[0][1], 0, 0, 0);
        acc[1][0] = __builtin_amdgcn_mfma_f32_16x16x32_bf16(a1, b0, acc[1][0], 0, 0, 0);
        acc[1][1] = __builtin_amdgcn_mfma_f32_16x16x32_bf16(a1, b1, acc[1][1], 0, 0, 0);
      }
    };

    stage(0, 0);
    for (int itk = 0; itk < NITER - 1; ++itk) {
      int cur = itk & 1;
      __builtin_amdgcn_s_barrier();       // prev compute on buf[cur^1] done
      stage(cur ^ 1, itk + 1);            // 8 async loads, stay in flight
      __builtin_amdgcn_s_waitcnt(0x0F78); // vmcnt(8): cur's loads landed
      __builtin_amdgcn_s_barrier();       // all waves' cur loads landed
      __builtin_amdgcn_sched_barrier(0);
      compute(cur);
    }
    __builtin_amdgcn_s_barrier();
    __builtin_amdgcn_s_waitcnt(0x0F70);   // vmcnt(0)
    __builtin_amdgcn_s_barrier();
    __builtin_amdgcn_sched_barrier(0);
    compute((NITER - 1) & 1);

    // Epilogue. C/D layout: col = lane&15 (j), row = quad*4 + reg (i).
    int jgc[2]; float sqj[2];
    #pragma unroll
    for (int tj = 0; tj < 2; tj++) {
      int jg = j0g + wj * 32 + tj * 16 + lr;
      jgc[tj] = imin(jg, jend - 1);
      sqj[tj] = sqg[jgc[tj]];
    }

    if (diag) {
      float colmax[2] = {0.f, 0.f};
      #pragma unroll
      for (int ti = 0; ti < 2; ti++) {
        #pragma unroll
        for (int r = 0; r < 4; r++) {
          int ig = i0g + wi * 32 + ti * 16 + quad * 4 + r;
          int igc = imin(ig, iend - 1);
          float sqi = sqg[igc];
          float apm = 0.f;
          #pragma unroll
          for (int tj = 0; tj < 2; tj++) {
            float d2 = sqi + sqj[tj] - 2.f * acc[ti][tj][r];
            float d = sqrtf(fmaxf(d2, 1e-12f));
            apm = fmaxf(apm, d);
            colmax[tj] = fmaxf(colmax[tj], d);
          }
          #pragma unroll
          for (int m = 1; m < 16; m <<= 1) apm = fmaxf(apm, __shfl_xor(apm, m));
          if (lr == 0) atomicMax(ap + igc, __float_as_uint(apm));
        }
      }
      // Off-diagonal sub-tile: symmetric contribution ap[j] = max over i.
      if (dcol) {
        #pragma unroll
        for (int tj = 0; tj < 2; tj++) {
          float v = colmax[tj];
          v = fmaxf(v, __shfl_xor(v, 16));
          v = fmaxf(v, __shfl_xor(v, 32));
          if (quad == 0) atomicMax(ap + jgc[tj], __float_as_uint(v));
        }
      }
    } else {
      float colmin[2] = {INFINITY, INFINITY};
      #pragma unroll
      for (int ti = 0; ti < 2; ti++) {
        #pragma unroll
        for (int r = 0; r < 4; r++) {
          int ig = i0g + wi * 32 + ti * 16 + quad * 4 + r;
          int igc = imin(ig, iend - 1);
          float sqi = sqg[igc];
          float anm = INFINITY;
          #pragma unroll
          for (int tj = 0; tj < 2; tj++) {
            float d2 = sqi + sqj[tj] - 2.f * acc[ti][tj][r];
            float d = sqrtf(fmaxf(d2, 1e-12f));
            anm = fminf(anm, d);
            colmin[tj] = fminf(colmin[tj], d);
          }
          #pragma unroll
          for (int m = 1; m < 16; m <<= 1) anm = fminf(anm, __shfl_xor(anm, m));
          if (lr == 0) atomicMin(an + igc, __float_as_uint(anm));
        }
      }
      #pragma unroll
      for (int tj = 0; tj < 2; tj++) {
        float v = colmin[tj];
        v = fminf(v, __shfl_xor(v, 16));
        v = fminf(v, __shfl_xor(v, 32));
        if (quad == 0) atomicMin(an + jgc[tj], __float_as_uint(v));
      }
    }
  }

  // ---- last-block ticket: final loss reduction --------------------------
  __syncthreads();
  if (t == 0) {
    __threadfence();
    int ticket = __hip_atomic_fetch_add(done, 1, __ATOMIC_ACQ_REL,
                                        __HIP_MEMORY_SCOPE_AGENT);
    s_islast = (ticket == GRID - 1);
  }
  __syncthreads();
  if (s_islast) {
    int has = flag[0];
    float s = 0.f;
    for (int i = t; i < N; i += 256) {
      unsigned int au = __hip_atomic_load(ap + i, __ATOMIC_RELAXED,
                                          __HIP_MEMORY_SCOPE_AGENT);
      unsigned int nu = __hip_atomic_load(an + i, __ATOMIC_RELAXED,
                                          __HIP_MEMORY_SCOPE_AGENT);
      float a = __uint_as_float(au);
      float bb = has ? __uint_as_float(nu) : 0.f;
      s += fmaxf(a - bb + MARGIN, 0.f);
    }
    #pragma unroll
    for (int m = 32; m; m >>= 1) s += __shfl_xor(s, m);
    if ((t & 63) == 0) wred[t >> 6] = s;
    __syncthreads();
    if (t == 0) out[0] = (wred[0] + wred[1] + wred[2] + wred[3]) / (float)N;
  }
}

// ---------------------------------------------------------------------------
extern "C" void kernel_launch(void* const* d_in, const int* in_sizes, int n_in,
                              void* d_out, int out_size, void* d_ws,
                              size_t ws_size, hipStream_t stream) {
  const float* X = (const float*)d_in[0];
  const int* tg = (const int*)d_in[1];
  float* out = (float*)d_out;

  char* ws = (char*)d_ws;
  __bf16* Xg = (__bf16*)ws;
  size_t o = (size_t)N * K * 2;
  float* sqg = (float*)(ws + o); o += (size_t)N * 4;
  unsigned int* ap = (unsigned int*)(ws + o); o += (size_t)N * 4;
  unsigned int* an = (unsigned int*)(ws + o); o += (size_t)N * 4;
  int* cnt = (int*)(ws + o); o += NC * 4;
  int* off = (int*)(ws + o); o += NC * 4;
  int* cur = (int*)(ws + o); o += NC * 4;
  int* flag = (int*)(ws + o); o += 4;
  int* done = (int*)(ws + o); o += 4;

  hist_kernel<<<1, 256, 0, stream>>>(tg, cnt, off, cur, flag, done);
  convert_kernel<<<N / 4, 256, 0, stream>>>(X, tg, Xg, sqg, ap, an, cur);
  gemm_reduce_kernel<<<GRID, 256, 0, stream>>>(Xg, sqg, cnt, off, ap, an,
                                               flag, done, out);
}

// Round 2
// 117.949 us; speedup vs baseline: 1.1986x; 1.1836x over previous
//
#include <hip/hip_runtime.h>
#include <hip/hip_bf16.h>
#include <math.h>

#define N 4096
#define K 2048
#define NC 32
#define MARGIN 0.3f

#define BK 128           // K elements per pipeline stage
#define NITER (K / BK)   // 16
#define DIAG_BLOCKS 192  // 32 classes x 6 upper-tri sub-tile pairs of 64
#define CROSS_BLOCKS 192 // 3 row-tiles x 64 col-tiles
#define GRID (DIAG_BLOCKS + CROSS_BLOCKS)

typedef float f32x4 __attribute__((ext_vector_type(4)));
typedef __bf16 bf16x8 __attribute__((ext_vector_type(8)));

__device__ __forceinline__ void glds16(const void* g, void* l) {
  __builtin_amdgcn_global_load_lds(
      (const __attribute__((address_space(1))) void*)g,
      (__attribute__((address_space(3))) void*)l, 16, 0, 0);
}

__device__ __forceinline__ int imin(int a, int b) { return a < b ? a : b; }

// ---------------------------------------------------------------------------
// Kernel 1: fp32 -> bf16 convert + class-sorted scatter + sum-of-squares +
// ap/an init. One WAVE per original row; destination position computed
// DETERMINISTICALLY by rank scan over the (L2-resident) target array:
//   pos(r) = #{r': tg[r'] < c} + #{r' < r: tg[r'] == c}
// -> no cursor atomics, no histogram prerequisite. Block 0 additionally
// computes cnt/off/flag/done for the gemm kernel (overlapped with the other
// blocks' conversion work). This removes the former hist_kernel dispatch.
// ---------------------------------------------------------------------------
__global__ __launch_bounds__(256) void convert_kernel(
    const float* __restrict__ X, const int* __restrict__ tg,
    __bf16* __restrict__ Xg, float* __restrict__ sqg,
    unsigned int* __restrict__ ap, unsigned int* __restrict__ an,
    int* __restrict__ cnt, int* __restrict__ off, int* __restrict__ flag,
    int* __restrict__ done) {
  __shared__ int h[NC];
  int t = threadIdx.x;
  int w = t >> 6, lane = t & 63;
  int row = blockIdx.x * 4 + w;
  const float4* xr = (const float4*)(X + (size_t)row * K);

  // 8 float4 loads in flight (lane covers 4 chunks of 8 floats).
  float4 v[8];
  #pragma unroll
  for (int q = 0; q < 4; q++) {
    int chunk = q * 64 + lane;
    v[2 * q]     = xr[chunk * 2];
    v[2 * q + 1] = xr[chunk * 2 + 1];
  }

  // Rank scan: position of this row in the class-sorted layout.
  int c = tg[row];
  const int4* tg4 = (const int4*)tg;
  int pc = 0;
  #pragma unroll 4
  for (int chunk = lane; chunk < N / 4; chunk += 64) {
    int4 tv = tg4[chunk];
    int base = chunk * 4;
    pc += (tv.x < c) + ((tv.x == c) & (base + 0 < row));
    pc += (tv.y < c) + ((tv.y == c) & (base + 1 < row));
    pc += (tv.z < c) + ((tv.z == c) & (base + 2 < row));
    pc += (tv.w < c) + ((tv.w == c) & (base + 3 < row));
  }

  float s = 0.f;
  bf16x8 b[4];
  #pragma unroll
  for (int q = 0; q < 4; q++) {
    float4 a0 = v[2 * q], a1 = v[2 * q + 1];
    s += a0.x * a0.x + a0.y * a0.y + a0.z * a0.z + a0.w * a0.w +
         a1.x * a1.x + a1.y * a1.y + a1.z * a1.z + a1.w * a1.w;
    b[q][0] = (__bf16)a0.x; b[q][1] = (__bf16)a0.y;
    b[q][2] = (__bf16)a0.z; b[q][3] = (__bf16)a0.w;
    b[q][4] = (__bf16)a1.x; b[q][5] = (__bf16)a1.y;
    b[q][6] = (__bf16)a1.z; b[q][7] = (__bf16)a1.w;
  }

  #pragma unroll
  for (int m = 32; m; m >>= 1) {
    s += __shfl_xor(s, m);
    pc += __shfl_xor(pc, m);
  }
  int pos = pc;

  bf16x8* dst = (bf16x8*)(Xg + (size_t)pos * K);
  #pragma unroll
  for (int q = 0; q < 4; q++) dst[q * 64 + lane] = b[q];

  if (lane == 0) {
    sqg[pos] = s;
    ap[pos] = 0u;           // identity for max of non-negative floats
    an[pos] = 0x7f800000u;  // +inf
  }

  // Block 0 side job: histogram -> cnt/off/flag/done for the gemm kernel.
  if (blockIdx.x == 0) {
    if (t < NC) h[t] = 0;
    __syncthreads();
    for (int i = t; i < N / 4; i += 256) {
      int4 v4 = tg4[i];
      atomicAdd(&h[v4.x], 1); atomicAdd(&h[v4.y], 1);
      atomicAdd(&h[v4.z], 1); atomicAdd(&h[v4.w], 1);
    }
    __syncthreads();
    if (t == 0) {
      int acc = 0;
      for (int cc = 0; cc < NC; cc++) {
        cnt[cc] = h[cc];
        off[cc] = acc;
        acc += h[cc];
      }
      int t0 = tg[0];
      flag[0] = (t0 == 0) ? (N - h[0] > 0) : (h[0] > 0);
      done[0] = 0;
    }
  }
}

// ---------------------------------------------------------------------------
// Kernel 2: class-bucketed 64x64 MFMA tiles, BK=128, double-buffered async
// global_load_lds pipeline with raw s_barrier + manual vmcnt (prefetch stays
// in flight across the barrier). XOR-swizzled LDS.
// Diag blocks enumerate only the UPPER TRIANGLE of sub-tile pairs
// (dist(i,j)==dist(j,i) bit-exactly); off-diagonal sub-tiles update ap from
// both the row-max and the column-max. Last block (ticket) does the final
// loss reduction.
// ---------------------------------------------------------------------------
__global__ __launch_bounds__(256) void gemm_reduce_kernel(
    const __bf16* __restrict__ Xg, const float* __restrict__ sqg,
    const int* __restrict__ cnt, const int* __restrict__ off,
    unsigned int* __restrict__ ap, unsigned int* __restrict__ an,
    const int* __restrict__ flag, int* __restrict__ done,
    float* __restrict__ out) {
  __shared__ __align__(16) __bf16 sA[2][64 * BK];  // 2 x 16 KiB
  __shared__ __align__(16) __bf16 sB[2][64 * BK];
  __shared__ int s_islast;
  __shared__ float wred[4];

  int b = blockIdx.x;
  int t = threadIdx.x;

  bool active = true, diag = true, dcol = false;
  int i0g = 0, iend = 1, j0g = 0, jend = 1;
  if (b < DIAG_BLOCKS) {
    int c = b / 6, p = b % 6;
    // p -> (sti,stj): (0,0),(0,1),(0,2),(1,1),(1,2),(2,2)
    int sti = (p < 3) ? 0 : (p < 5 ? 1 : 2);
    int stj = (p < 3) ? p : (p < 5 ? p - 2 : 2);
    int o = off[c], n = cnt[c];
    if (n == 0 || sti * 64 >= n || stj * 64 >= n) active = false;
    i0g = o + sti * 64; iend = o + n;
    j0g = o + stj * 64; jend = o + n;
    dcol = (sti != stj);
  } else {
    int idx = b - DIAG_BLOCKS;
    int it = idx >> 6, jt = idx & 63;
    int n0 = cnt[0];
    int j0 = n0 + jt * 64;
    if (n0 == 0 || it * 64 >= n0 || j0 >= N) active = false;
    i0g = it * 64; iend = n0;
    j0g = j0; jend = N;
    diag = false;
  }

  if (active) {
    int w = t >> 6, l = t & 63;
    int wi = w >> 1, wj = w & 1;
    int quad = l >> 4, lr = l & 15;

    // Staging: thread t fills LDS (row_l = r*16 + t>>4, cb_l = t&15) from
    // global col-block cb_g = cb_l ^ (row_l & 15). row_l&15 == t>>4.
    const char* gA[4]; const char* gB[4];
    int rr = t >> 4, cbl = t & 15;
    int cbg = cbl ^ rr;
    #pragma unroll
    for (int r = 0; r < 4; r++) {
      int row_l = r * 16 + rr;
      int ra = imin(i0g + row_l, iend - 1);
      int rb = imin(j0g + row_l, jend - 1);
      gA[r] = (const char*)(Xg + (size_t)ra * K) + cbg * 16;
      gB[r] = (const char*)(Xg + (size_t)rb * K) + cbg * 16;
    }

    // Fragment LDS byte offsets: row*256 + (cb ^ (row&15))*16, row&15 == lr.
    int aoff[2][4], boff[2][4];
    #pragma unroll
    for (int ti = 0; ti < 2; ti++)
      #pragma unroll
      for (int kc = 0; kc < 4; kc++) {
        int cb = kc * 4 + quad;
        int sw = (cb ^ lr) * 16;
        aoff[ti][kc] = (wi * 32 + ti * 16 + lr) * 256 + sw;
        boff[ti][kc] = (wj * 32 + ti * 16 + lr) * 256 + sw;
      }

    f32x4 acc[2][2];
    acc[0][0] = (f32x4)0.f; acc[0][1] = (f32x4)0.f;
    acc[1][0] = (f32x4)0.f; acc[1][1] = (f32x4)0.f;

    auto stage = [&](int buf, int itk) {
      int koff = itk * (BK * 2);
      char* la = (char*)sA + buf * 16384 + t * 16;
      char* lb = (char*)sB + buf * 16384 + t * 16;
      #pragma unroll
      for (int r = 0; r < 4; r++) {
        glds16(gA[r] + koff, la + r * 4096);
        glds16(gB[r] + koff, lb + r * 4096);
      }
    };

    auto compute = [&](int buf) {
      const char* bufA = (const char*)sA + buf * 16384;
      const char* bufB = (const char*)sB + buf * 16384;
      #pragma unroll
      for (int kc = 0; kc < 4; kc++) {
        bf16x8 a0 = *(const bf16x8*)(bufA + aoff[0][kc]);
        bf16x8 a1 = *(const bf16x8*)(bufA + aoff[1][kc]);
        bf16x8 b0 = *(const bf16x8*)(bufB + boff[0][kc]);
        bf16x8 b1 = *(const bf16x8*)(bufB + boff[1][kc]);
        acc[0][0] = __builtin_amdgcn_mfma_f32_16x16x32_bf16(a0, b0, acc[0][0], 0, 0, 0);
        acc[0][1] = __builtin_amdgcn_mfma_f32_16x16x32_bf16(a0, b1, acc[0][1], 0, 0, 0);
        acc[1][0] = __builtin_amdgcn_mfma_f32_16x16x32_bf16(a1, b0, acc[1][0], 0, 0, 0);
        acc[1][1] = __builtin_amdgcn_mfma_f32_16x16x32_bf16(a1, b1, acc[1][1], 0, 0, 0);
      }
    };

    stage(0, 0);
    for (int itk = 0; itk < NITER - 1; ++itk) {
      int cur = itk & 1;
      __builtin_amdgcn_s_barrier();       // prev compute on buf[cur^1] done
      stage(cur ^ 1, itk + 1);            // 8 async loads, stay in flight
      __builtin_amdgcn_s_waitcnt(0x0F78); // vmcnt(8): cur's loads landed
      __builtin_amdgcn_s_barrier();       // all waves' cur loads landed
      __builtin_amdgcn_sched_barrier(0);
      compute(cur);
    }
    __builtin_amdgcn_s_barrier();
    __builtin_amdgcn_s_waitcnt(0x0F70);   // vmcnt(0)
    __builtin_amdgcn_s_barrier();
    __builtin_amdgcn_sched_barrier(0);
    compute((NITER - 1) & 1);

    // Epilogue. C/D layout: col = lane&15 (j), row = quad*4 + reg (i).
    int jgc[2]; float sqj[2];
    #pragma unroll
    for (int tj = 0; tj < 2; tj++) {
      int jg = j0g + wj * 32 + tj * 16 + lr;
      jgc[tj] = imin(jg, jend - 1);
      sqj[tj] = sqg[jgc[tj]];
    }

    if (diag) {
      float colmax[2] = {0.f, 0.f};
      #pragma unroll
      for (int ti = 0; ti < 2; ti++) {
        #pragma unroll
        for (int r = 0; r < 4; r++) {
          int ig = i0g + wi * 32 + ti * 16 + quad * 4 + r;
          int igc = imin(ig, iend - 1);
          float sqi = sqg[igc];
          float apm = 0.f;
          #pragma unroll
          for (int tj = 0; tj < 2; tj++) {
            float d2 = sqi + sqj[tj] - 2.f * acc[ti][tj][r];
            float d = sqrtf(fmaxf(d2, 1e-12f));
            apm = fmaxf(apm, d);
            colmax[tj] = fmaxf(colmax[tj], d);
          }
          #pragma unroll
          for (int m = 1; m < 16; m <<= 1) apm = fmaxf(apm, __shfl_xor(apm, m));
          if (lr == 0) atomicMax(ap + igc, __float_as_uint(apm));
        }
      }
      // Off-diagonal sub-tile: symmetric contribution ap[j] = max over i.
      if (dcol) {
        #pragma unroll
        for (int tj = 0; tj < 2; tj++) {
          float v = colmax[tj];
          v = fmaxf(v, __shfl_xor(v, 16));
          v = fmaxf(v, __shfl_xor(v, 32));
          if (quad == 0) atomicMax(ap + jgc[tj], __float_as_uint(v));
        }
      }
    } else {
      float colmin[2] = {INFINITY, INFINITY};
      #pragma unroll
      for (int ti = 0; ti < 2; ti++) {
        #pragma unroll
        for (int r = 0; r < 4; r++) {
          int ig = i0g + wi * 32 + ti * 16 + quad * 4 + r;
          int igc = imin(ig, iend - 1);
          float sqi = sqg[igc];
          float anm = INFINITY;
          #pragma unroll
          for (int tj = 0; tj < 2; tj++) {
            float d2 = sqi + sqj[tj] - 2.f * acc[ti][tj][r];
            float d = sqrtf(fmaxf(d2, 1e-12f));
            anm = fminf(anm, d);
            colmin[tj] = fminf(colmin[tj], d);
          }
          #pragma unroll
          for (int m = 1; m < 16; m <<= 1) anm = fminf(anm, __shfl_xor(anm, m));
          if (lr == 0) atomicMin(an + igc, __float_as_uint(anm));
        }
      }
      #pragma unroll
      for (int tj = 0; tj < 2; tj++) {
        float v = colmin[tj];
        v = fminf(v, __shfl_xor(v, 16));
        v = fminf(v, __shfl_xor(v, 32));
        if (quad == 0) atomicMin(an + jgc[tj], __float_as_uint(v));
      }
    }
  }

  // ---- last-block ticket: final loss reduction --------------------------
  __syncthreads();
  if (t == 0) {
    __threadfence();
    int ticket = __hip_atomic_fetch_add(done, 1, __ATOMIC_ACQ_REL,
                                        __HIP_MEMORY_SCOPE_AGENT);
    s_islast = (ticket == GRID - 1);
  }
  __syncthreads();
  if (s_islast) {
    int has = flag[0];
    float s = 0.f;
    for (int i = t; i < N; i += 256) {
      unsigned int au = __hip_atomic_load(ap + i, __ATOMIC_RELAXED,
                                          __HIP_MEMORY_SCOPE_AGENT);
      unsigned int nu = __hip_atomic_load(an + i, __ATOMIC_RELAXED,
                                          __HIP_MEMORY_SCOPE_AGENT);
      float a = __uint_as_float(au);
      float bb = has ? __uint_as_float(nu) : 0.f;
      s += fmaxf(a - bb + MARGIN, 0.f);
    }
    #pragma unroll
    for (int m = 32; m; m >>= 1) s += __shfl_xor(s, m);
    if ((t & 63) == 0) wred[t >> 6] = s;
    __syncthreads();
    if (t == 0) out[0] = (wred[0] + wred[1] + wred[2] + wred[3]) / (float)N;
  }
}

// ---------------------------------------------------------------------------
extern "C" void kernel_launch(void* const* d_in, const int* in_sizes, int n_in,
                              void* d_out, int out_size, void* d_ws,
                              size_t ws_size, hipStream_t stream) {
  const float* X = (const float*)d_in[0];
  const int* tg = (const int*)d_in[1];
  float* out = (float*)d_out;

  char* ws = (char*)d_ws;
  __bf16* Xg = (__bf16*)ws;
  size_t o = (size_t)N * K * 2;
  float* sqg = (float*)(ws + o); o += (size_t)N * 4;
  unsigned int* ap = (unsigned int*)(ws + o); o += (size_t)N * 4;
  unsigned int* an = (unsigned int*)(ws + o); o += (size_t)N * 4;
  int* cnt = (int*)(ws + o); o += NC * 4;
  int* off = (int*)(ws + o); o += NC * 4;
  int* flag = (int*)(ws + o); o += 4;
  int* done = (int*)(ws + o); o += 4;

  convert_kernel<<<N / 4, 256, 0, stream>>>(X, tg, Xg, sqg, ap, an, cnt, off,
                                            flag, done);
  gemm_reduce_kernel<<<GRID, 256, 0, stream>>>(Xg, sqg, cnt, off, ap, an,
                                               flag, done, out);
}